// Round 15
// baseline (307.617 us; speedup 1.0000x reference)
//
#include <hip/hip_runtime.h>

#define NN 50000
#define NE 800000
#define C 128
#define CAP 64                           // fixed edge capacity per node (P(deg>=64) ~ 4e-18)
#define EB2 ((NE / 2 + 255) / 256)       // 1563 edge blocks (2 edges/thread)
#define SPLITB 1563                      // x-split blocks
#define WB 96                            // W-split blocks: 6*16384 floats / 4 / 256
#define ASTRIDE 136                      // bf16 elems per LDS A row

typedef __attribute__((ext_vector_type(8))) short bf16x8;
typedef __attribute__((ext_vector_type(4))) float f32x4;
typedef unsigned short ushort;

__device__ inline ushort bf16_rn(float f) {
    unsigned u = __builtin_bit_cast(unsigned, f);
    u += 0x7FFF + ((u >> 16) & 1);
    return (ushort)(u >> 16);
}
__device__ inline void split_bf16(float f, ushort& hi, ushort& lo) {
    hi = bf16_rn(f);
    float hif = __builtin_bit_cast(float, (unsigned)hi << 16);
    lo = bf16_rn(f - hif);               // residual, ~2^-17 rel total
}
__device__ inline float bf_lo(unsigned u) { return __builtin_bit_cast(float, u << 16); }
__device__ inline float bf_hi(unsigned u) { return __builtin_bit_cast(float, u & 0xFFFF0000u); }

// ---- fused prep: count+place edges (single pass!) + split x + split W ----
// Bucket slot comes straight from the atomic return -> no scan, no pos array, no
// second edge pass. The scattered col store is fire-and-forget and overlaps the
// atomic-return wait bubbles.

__global__ __launch_bounds__(256)
void prep_kernel(const int* __restrict__ src, const int* __restrict__ dst,
                 const float* __restrict__ x,
                 const float* __restrict__ W0, const float* __restrict__ W1,
                 const float* __restrict__ W2, const float* __restrict__ W3,
                 const float* __restrict__ W4, const float* __restrict__ W5,
                 int* __restrict__ deg, int* __restrict__ col,
                 ushort* __restrict__ Ah, ushort* __restrict__ Al,
                 ushort* __restrict__ Wh, ushort* __restrict__ Wl) {
    int t = threadIdx.x;
    if (blockIdx.x < EB2) {
        // edge phase: 2 edges/thread; count and place in one step
        int e0 = (blockIdx.x * 256 + t) * 2;
        if (e0 < NE) {
            int2 d2 = *(const int2*)(dst + e0);
            int2 s2 = *(const int2*)(src + e0);
            int p0 = atomicAdd(&deg[d2.x], 1);
            int p1 = atomicAdd(&deg[d2.y], 1);
            if (p0 < CAP) col[d2.x * CAP + p0] = s2.x;
            if (p1 < CAP) col[d2.y * CAP + p1] = s2.y;
        }
    } else if (blockIdx.x < EB2 + SPLITB) {
        // x split phase (grid-stride over 1.6M f32x4), row-major hi/lo
        int tid = (blockIdx.x - EB2) * 256 + t;
        const int total = NN * C / 4;
        for (int i = tid; i < total; i += SPLITB * 256) {
            f32x4 v = ((const f32x4*)x)[i];
            ushort h0, h1, h2, h3, l0, l1, l2, l3;
            split_bf16(v.x, h0, l0);
            split_bf16(v.y, h1, l1);
            split_bf16(v.z, h2, l2);
            split_bf16(v.w, h3, l3);
            *(uint2*)(Ah + (size_t)i * 4) = make_uint2((unsigned)h0 | ((unsigned)h1 << 16),
                                                       (unsigned)h2 | ((unsigned)h3 << 16));
            *(uint2*)(Al + (size_t)i * 4) = make_uint2((unsigned)l0 | ((unsigned)l1 << 16),
                                                       (unsigned)l2 | ((unsigned)l3 << 16));
        }
    } else {
        // W split phase: 6 matrices x 16384 floats = 24576 f32x4, exactly WB*256 threads
        const float* Ws[6] = {W0, W1, W2, W3, W4, W5};
        int i = (blockIdx.x - EB2 - SPLITB) * 256 + t;
        int mat = i >> 12;
        f32x4 v = ((const f32x4*)Ws[mat])[i & 4095];
        ushort h0, h1, h2, h3, l0, l1, l2, l3;
        split_bf16(v.x, h0, l0);
        split_bf16(v.y, h1, l1);
        split_bf16(v.z, h2, l2);
        split_bf16(v.w, h3, l3);
        *(uint2*)(Wh + (size_t)i * 4) = make_uint2((unsigned)h0 | ((unsigned)h1 << 16),
                                                   (unsigned)h2 | ((unsigned)h3 << 16));
        *(uint2*)(Wl + (size_t)i * 4) = make_uint2((unsigned)l0 | ((unsigned)l1 << 16),
                                                   (unsigned)l2 | ((unsigned)l3 << 16));
    }
}

// ---- mean aggregation: one wave per node, 4 edge-rows per VMEM instr (row-major) ----
// Row = 256 B of bf16-hi. 16 lanes x uint4 per edge-row; quad = lane>>4 picks edge;
// 2 loads in flight = 8 edge-rows. Cross-quad shfl reduce.
// Epilogue: mean -> split hi/lo -> 16B stores (feeds gemm A-operand directly).

__global__ __launch_bounds__(256)
void agg_kernel(const ushort* __restrict__ xh, const int* __restrict__ deg,
                const int* __restrict__ col,
                ushort* __restrict__ aggh, ushort* __restrict__ aggl, int nodes) {
    int node = (blockIdx.x * blockDim.x + threadIdx.x) >> 6;
    int lane = threadIdx.x & 63;
    if (node >= nodes) return;
    int quad = lane >> 4;        // which edge within a group of 4
    int ql   = lane & 15;        // channel group: ch [ql*8, ql*8+8)
    int d = min(deg[node], CAP);
    int start = node * CAP;
    int end = start + d;
    const uint4* xr = (const uint4*)xh;   // row = 16 uint4
    float a0=0,a1=0,a2=0,a3=0,a4=0,a5=0,a6=0,a7=0;
    int e = start;
    for (; e + 7 < end; e += 8) {
        int i0 = col[e + quad];
        int i1 = col[e + 4 + quad];
        uint4 u0 = xr[(size_t)i0 * 16 + ql];
        uint4 u1 = xr[(size_t)i1 * 16 + ql];
        a0 += bf_lo(u0.x) + bf_lo(u1.x); a1 += bf_hi(u0.x) + bf_hi(u1.x);
        a2 += bf_lo(u0.y) + bf_lo(u1.y); a3 += bf_hi(u0.y) + bf_hi(u1.y);
        a4 += bf_lo(u0.z) + bf_lo(u1.z); a5 += bf_hi(u0.z) + bf_hi(u1.z);
        a6 += bf_lo(u0.w) + bf_lo(u1.w); a7 += bf_hi(u0.w) + bf_hi(u1.w);
    }
    for (; e + 3 < end; e += 4) {
        uint4 u = xr[(size_t)col[e + quad] * 16 + ql];
        a0 += bf_lo(u.x); a1 += bf_hi(u.x);
        a2 += bf_lo(u.y); a3 += bf_hi(u.y);
        a4 += bf_lo(u.z); a5 += bf_hi(u.z);
        a6 += bf_lo(u.w); a7 += bf_hi(u.w);
    }
    int rem = end - e;           // 0..3
    if (quad < rem) {
        uint4 u = xr[(size_t)col[e + quad] * 16 + ql];
        a0 += bf_lo(u.x); a1 += bf_hi(u.x);
        a2 += bf_lo(u.y); a3 += bf_hi(u.y);
        a4 += bf_lo(u.z); a5 += bf_hi(u.z);
        a6 += bf_lo(u.w); a7 += bf_hi(u.w);
    }
    // reduce across the 4 quads (lanes ql, ql+16, ql+32, ql+48)
    a0 += __shfl_xor(a0, 16, 64); a0 += __shfl_xor(a0, 32, 64);
    a1 += __shfl_xor(a1, 16, 64); a1 += __shfl_xor(a1, 32, 64);
    a2 += __shfl_xor(a2, 16, 64); a2 += __shfl_xor(a2, 32, 64);
    a3 += __shfl_xor(a3, 16, 64); a3 += __shfl_xor(a3, 32, 64);
    a4 += __shfl_xor(a4, 16, 64); a4 += __shfl_xor(a4, 32, 64);
    a5 += __shfl_xor(a5, 16, 64); a5 += __shfl_xor(a5, 32, 64);
    a6 += __shfl_xor(a6, 16, 64); a6 += __shfl_xor(a6, 32, 64);
    a7 += __shfl_xor(a7, 16, 64); a7 += __shfl_xor(a7, 32, 64);
    if (quad == 0) {
        float inv = 1.0f / (float)max(d, 1);
        float m[8] = {a0*inv, a1*inv, a2*inv, a3*inv, a4*inv, a5*inv, a6*inv, a7*inv};
        ushort h[8], o[8];
        #pragma unroll
        for (int j = 0; j < 8; ++j) split_bf16(m[j], h[j], o[j]);
        size_t off = (size_t)node * C + ql * 8;
        *(uint4*)(aggh + off) = make_uint4((unsigned)h[0] | ((unsigned)h[1] << 16),
                                           (unsigned)h[2] | ((unsigned)h[3] << 16),
                                           (unsigned)h[4] | ((unsigned)h[5] << 16),
                                           (unsigned)h[6] | ((unsigned)h[7] << 16));
        *(uint4*)(aggl + off) = make_uint4((unsigned)o[0] | ((unsigned)o[1] << 16),
                                           (unsigned)o[2] | ((unsigned)o[3] << 16),
                                           (unsigned)o[4] | ((unsigned)o[5] << 16),
                                           (unsigned)o[6] | ((unsigned)o[7] << 16));
    }
}

// ---- fused dual GEMM + bias + PReLU via split-bf16 MFMA ----
// out = prelu( A@Wl.T + bl + X@Wr.T ); operands AND weights pre-split hi/lo (row-major).
// block = 256 (4 waves), tile 64 rows x 128 cols; wave = 32-col strip.

__global__ __launch_bounds__(256, 3)
void gemm_kernel(const ushort* __restrict__ Ah, const ushort* __restrict__ Al,
                 const ushort* __restrict__ Xh, const ushort* __restrict__ Xl,
                 const ushort* __restrict__ Wlh, const ushort* __restrict__ Wll,
                 const ushort* __restrict__ Wrh, const ushort* __restrict__ Wrl,
                 const float* __restrict__ bl, const float* __restrict__ slope,
                 float* __restrict__ outf, ushort* __restrict__ outh,
                 ushort* __restrict__ outl, int rows) {
    __shared__ ushort Ahi[64 * ASTRIDE];
    __shared__ ushort Alo[64 * ASTRIDE];
    int t = threadIdx.x;
    int lane = t & 63;
    int w = t >> 6;
    int l = lane & 15;
    int q = lane >> 4;
    int row0 = blockIdx.x * 64;

    f32x4 acc[4][2];
    #pragma unroll
    for (int mt = 0; mt < 4; ++mt)
        #pragma unroll
        for (int nt = 0; nt < 2; ++nt)
            acc[mt][nt] = (f32x4){0.f, 0.f, 0.f, 0.f};

    #pragma unroll
    for (int mat = 0; mat < 2; ++mat) {
        const ushort* WH = mat ? Wrh : Wlh;
        const ushort* WL = mat ? Wrl : Wll;
        const ushort* Ph = mat ? Xh : Ah;
        const ushort* Pl = mat ? Xl : Al;

        // W fragments direct from pre-split arrays: B[k][n], n = lane&15, k = q*8+j
        bf16x8 bhi[2][4], blo[2][4];
        #pragma unroll
        for (int nt = 0; nt < 2; ++nt) {
            int n = w * 32 + nt * 16 + l;
            const ushort* wp = WH + (size_t)n * C + q * 8;
            const ushort* wq = WL + (size_t)n * C + q * 8;
            #pragma unroll
            for (int kb = 0; kb < 4; ++kb) {
                bhi[nt][kb] = *(const bf16x8*)(wp + kb * 32);
                blo[nt][kb] = *(const bf16x8*)(wq + kb * 32);
            }
        }

        __syncthreads();                 // protect previous mat's frag reads
        int ar = t >> 2;                 // row 0..63
        int aq = t & 3;                  // k quarter: 32 ushorts
        int r = min(row0 + ar, rows - 1);
        ushort* dh = Ahi + ar * ASTRIDE + aq * 32;
        ushort* dl = Alo + ar * ASTRIDE + aq * 32;
        const ushort* ph = Ph + (size_t)r * C + aq * 32;
        const ushort* pl = Pl + (size_t)r * C + aq * 32;
        #pragma unroll
        for (int i = 0; i < 4; ++i) {    // 4 x uint4 = 32 ushorts
            *(uint4*)(dh + i * 8) = *(const uint4*)(ph + i * 8);
            *(uint4*)(dl + i * 8) = *(const uint4*)(pl + i * 8);
        }
        __syncthreads();

        // K loop: 4 k-blocks x 4 m-tiles x 2 n-tiles x 3 products
        #pragma unroll
        for (int kb = 0; kb < 4; ++kb) {
            #pragma unroll
            for (int mt = 0; mt < 4; ++mt) {
                int off = (mt * 16 + l) * ASTRIDE + kb * 32 + q * 8;
                bf16x8 ahi = *(const bf16x8*)(Ahi + off);
                bf16x8 alo = *(const bf16x8*)(Alo + off);
                #pragma unroll
                for (int nt = 0; nt < 2; ++nt) {
                    acc[mt][nt] = __builtin_amdgcn_mfma_f32_16x16x32_bf16(ahi, bhi[nt][kb], acc[mt][nt], 0, 0, 0);
                    acc[mt][nt] = __builtin_amdgcn_mfma_f32_16x16x32_bf16(alo, bhi[nt][kb], acc[mt][nt], 0, 0, 0);
                    acc[mt][nt] = __builtin_amdgcn_mfma_f32_16x16x32_bf16(ahi, blo[nt][kb], acc[mt][nt], 0, 0, 0);
                }
            }
        }
    }

    // epilogue: bias + PReLU; write fp32 (final layer) or hi/lo (hidden layers)
    #pragma unroll
    for (int nt = 0; nt < 2; ++nt) {
        int n = w * 32 + nt * 16 + l;
        float b = bl[n], s = slope[n];
        #pragma unroll
        for (int mt = 0; mt < 4; ++mt) {
            #pragma unroll
            for (int rg = 0; rg < 4; ++rg) {
                int r = row0 + mt * 16 + q * 4 + rg;
                if (r < rows) {
                    float v = acc[mt][nt][rg] + b;
                    v = v > 0.f ? v : s * v;
                    if (outf) {
                        outf[(size_t)r * C + n] = v;
                    } else {
                        ushort hh, ll;
                        split_bf16(v, hh, ll);
                        outh[(size_t)r * C + n] = hh;
                        outl[(size_t)r * C + n] = ll;
                    }
                }
            }
        }
    }
}

// ---------------- launch ----------------

extern "C" void kernel_launch(void* const* d_in, const int* in_sizes, int n_in,
                              void* d_out, int out_size, void* d_ws, size_t ws_size,
                              hipStream_t stream) {
    const float* x   = (const float*)d_in[0];
    const int*   src = (const int*)d_in[1];
    const int*   dst = src + NE;
    const float* Wl[3] = {(const float*)d_in[3], (const float*)d_in[7],  (const float*)d_in[11]};
    const float* bl[3] = {(const float*)d_in[4], (const float*)d_in[8],  (const float*)d_in[12]};
    const float* Wr[3] = {(const float*)d_in[5], (const float*)d_in[9],  (const float*)d_in[13]};
    const float* sl[3] = {(const float*)d_in[6], (const float*)d_in[10], (const float*)d_in[14]};

    int*   deg     = (int*)d_ws;             // 50016
    int*   col     = deg + 50016;            // NN*CAP = 3.2M ints (fixed-capacity buckets)
    ushort* Whs    = (ushort*)(col + NN * CAP);  // 6*16384 pre-split W hi
    ushort* Wls    = Whs + 6 * 16384;        // 6*16384 pre-split W lo
    ushort* Gh     = Wls + 6 * 16384;        // agg hi, NN*C
    ushort* Gl     = Gh + (size_t)NN * C;    // agg lo
    ushort* Ah     = Gl + (size_t)NN * C;    // ping hi
    ushort* Al     = Ah + (size_t)NN * C;    // ping lo
    ushort* Bh     = Al + (size_t)NN * C;    // pong hi
    ushort* Bl     = Bh + (size_t)NN * C;    // pong lo

    hipMemsetAsync(deg, 0, 50016 * sizeof(int), stream);

    // W order: Wl0, Wr0, Wl1, Wr1, Wl2, Wr2
    prep_kernel<<<EB2 + SPLITB + WB, 256, 0, stream>>>(
        src, dst, x, Wl[0], Wr[0], Wl[1], Wr[1], Wl[2], Wr[2],
        deg, col, Ah, Al, Whs, Wls);

    int rows_out = out_size / C;             // 1024

    // layer 0: A -> B
    agg_kernel<<<(NN + 3) / 4, 256, 0, stream>>>(Ah, deg, col, Gh, Gl, NN);
    gemm_kernel<<<(NN + 63) / 64, 256, 0, stream>>>(Gh, Gl, Ah, Al,
                                                    Whs + 0 * 16384, Wls + 0 * 16384,
                                                    Whs + 1 * 16384, Wls + 1 * 16384,
                                                    bl[0], sl[0], nullptr, Bh, Bl, NN);

    // layer 1: B -> A
    agg_kernel<<<(NN + 3) / 4, 256, 0, stream>>>(Bh, deg, col, Gh, Gl, NN);
    gemm_kernel<<<(NN + 63) / 64, 256, 0, stream>>>(Gh, Gl, Bh, Bl,
                                                    Whs + 2 * 16384, Wls + 2 * 16384,
                                                    Whs + 3 * 16384, Wls + 3 * 16384,
                                                    bl[1], sl[1], nullptr, Ah, Al, NN);

    // layer 2: A -> d_out (first rows_out nodes only)
    agg_kernel<<<(rows_out + 3) / 4, 256, 0, stream>>>(Ah, deg, col, Gh, Gl, rows_out);
    gemm_kernel<<<(rows_out + 63) / 64, 256, 0, stream>>>(Gh, Gl, Ah, Al,
                                                          Whs + 4 * 16384, Wls + 4 * 16384,
                                                          Whs + 5 * 16384, Wls + 5 * 16384,
                                                          bl[2], sl[2], (float*)d_out, nullptr, nullptr,
                                                          rows_out);
}

// Round 16
// 292.921 us; speedup vs baseline: 1.0502x; 1.0502x over previous
//
#include <hip/hip_runtime.h>

#define NN 50000
#define NE 800000
#define C 128
#define CAP 64                           // fixed edge capacity per node (P(deg>=64) ~ 4e-18)
#define EB2 ((NE / 2 + 255) / 256)       // 1563 edge blocks (2 edges/thread)
#define SPLITB 1563                      // x-split blocks
#define WB 96                            // W-split blocks: 6*16384 floats / 4 / 256
#define EB4 ((NE / 4 + 255) / 256)       // 782 fill blocks (4 edges/thread)
#define ASTRIDE 136                      // bf16 elems per LDS A row

typedef __attribute__((ext_vector_type(8))) short bf16x8;
typedef __attribute__((ext_vector_type(4))) float f32x4;
typedef unsigned short ushort;

__device__ inline ushort bf16_rn(float f) {
    unsigned u = __builtin_bit_cast(unsigned, f);
    u += 0x7FFF + ((u >> 16) & 1);
    return (ushort)(u >> 16);
}
__device__ inline void split_bf16(float f, ushort& hi, ushort& lo) {
    hi = bf16_rn(f);
    float hif = __builtin_bit_cast(float, (unsigned)hi << 16);
    lo = bf16_rn(f - hif);               // residual, ~2^-17 rel total
}
__device__ inline float bf_lo(unsigned u) { return __builtin_bit_cast(float, u << 16); }
__device__ inline float bf_hi(unsigned u) { return __builtin_bit_cast(float, u & 0xFFFF0000u); }

// ---- fused prep: count_pos (edges) + split x + split W (R14 two-pass build) ----

__global__ __launch_bounds__(256)
void prep_kernel(const int* __restrict__ dst, const float* __restrict__ x,
                 const float* __restrict__ W0, const float* __restrict__ W1,
                 const float* __restrict__ W2, const float* __restrict__ W3,
                 const float* __restrict__ W4, const float* __restrict__ W5,
                 int* __restrict__ deg, int* __restrict__ pos,
                 ushort* __restrict__ Ah, ushort* __restrict__ Al,
                 ushort* __restrict__ Wh, ushort* __restrict__ Wl) {
    int t = threadIdx.x;
    if (blockIdx.x < EB2) {
        int e0 = (blockIdx.x * 256 + t) * 2;
        if (e0 < NE) {
            int2 d2 = *(const int2*)(dst + e0);
            int p0 = atomicAdd(&deg[d2.x], 1);
            int p1 = atomicAdd(&deg[d2.y], 1);
            *(int2*)(pos + e0) = make_int2(p0, p1);
        }
    } else if (blockIdx.x < EB2 + SPLITB) {
        int tid = (blockIdx.x - EB2) * 256 + t;
        const int total = NN * C / 4;
        for (int i = tid; i < total; i += SPLITB * 256) {
            f32x4 v = ((const f32x4*)x)[i];
            ushort h0, h1, h2, h3, l0, l1, l2, l3;
            split_bf16(v.x, h0, l0);
            split_bf16(v.y, h1, l1);
            split_bf16(v.z, h2, l2);
            split_bf16(v.w, h3, l3);
            *(uint2*)(Ah + (size_t)i * 4) = make_uint2((unsigned)h0 | ((unsigned)h1 << 16),
                                                       (unsigned)h2 | ((unsigned)h3 << 16));
            *(uint2*)(Al + (size_t)i * 4) = make_uint2((unsigned)l0 | ((unsigned)l1 << 16),
                                                       (unsigned)l2 | ((unsigned)l3 << 16));
        }
    } else {
        const float* Ws[6] = {W0, W1, W2, W3, W4, W5};
        int i = (blockIdx.x - EB2 - SPLITB) * 256 + t;
        int mat = i >> 12;
        f32x4 v = ((const f32x4*)Ws[mat])[i & 4095];
        ushort h0, h1, h2, h3, l0, l1, l2, l3;
        split_bf16(v.x, h0, l0);
        split_bf16(v.y, h1, l1);
        split_bf16(v.z, h2, l2);
        split_bf16(v.w, h3, l3);
        *(uint2*)(Wh + (size_t)i * 4) = make_uint2((unsigned)h0 | ((unsigned)h1 << 16),
                                                   (unsigned)h2 | ((unsigned)h3 << 16));
        *(uint2*)(Wl + (size_t)i * 4) = make_uint2((unsigned)l0 | ((unsigned)l1 << 16),
                                                   (unsigned)l2 | ((unsigned)l3 << 16));
    }
}

// ---- fill: fixed-capacity buckets; 4 edges/thread; stores independent of atomics ----

__global__ __launch_bounds__(256)
void fill_kernel(const int* __restrict__ src, const int* __restrict__ dst,
                 const int* __restrict__ pos, int* __restrict__ col) {
    int e0 = (blockIdx.x * 256 + threadIdx.x) * 4;
    if (e0 >= NE) return;
    int4 da = *(const int4*)(dst + e0);
    int4 sa = *(const int4*)(src + e0);
    int4 pa = *(const int4*)(pos + e0);
    if (pa.x < CAP) col[da.x * CAP + pa.x] = sa.x;
    if (pa.y < CAP) col[da.y * CAP + pa.y] = sa.y;
    if (pa.z < CAP) col[da.z * CAP + pa.z] = sa.z;
    if (pa.w < CAP) col[da.w * CAP + pa.w] = sa.w;
}

// ---- mark: needed[] = nodes 0..1023 plus their in-neighbors (for layer-1 pruning) ----

__global__ __launch_bounds__(256)
void mark_kernel(const int* __restrict__ deg, const int* __restrict__ col,
                 int* __restrict__ needed, int rows_out) {
    int i = blockIdx.x * 256 + threadIdx.x;   // i over rows_out*CAP slots
    int n = i / CAP;
    int s = i - n * CAP;
    if (n >= rows_out) return;
    if (s == 0) needed[n] = 1;
    if (s < min(deg[n], CAP)) needed[col[n * CAP + s]] = 1;
}

// ---- compact: needed -> list (order irrelevant; wave-coalesced atomic append) ----

__global__ __launch_bounds__(256)
void compact_kernel(const int* __restrict__ needed, int* __restrict__ list,
                    int* __restrict__ cnt) {
    int i = blockIdx.x * 256 + threadIdx.x;
    if (i < NN && needed[i]) {
        int p = atomicAdd(cnt, 1);
        list[p] = i;
    }
}

// ---- mean aggregation: one wave per (listed) node, 4 edge-rows per VMEM instr ----
// Row = 256 B of bf16-hi. 16 lanes x uint4 per edge-row; quad = lane>>4 picks edge.
// list!=null: process list[i] nodes (worst-case grid, early exit on *countp).
// Epilogue: mean -> split hi/lo -> 16B stores at ORIGINAL node offsets.

__global__ __launch_bounds__(256)
void agg_kernel(const ushort* __restrict__ xh, const int* __restrict__ deg,
                const int* __restrict__ col,
                const int* __restrict__ list, const int* __restrict__ countp,
                ushort* __restrict__ aggh, ushort* __restrict__ aggl, int nodes) {
    int i = (blockIdx.x * blockDim.x + threadIdx.x) >> 6;
    int lane = threadIdx.x & 63;
    int cnt = list ? *countp : nodes;
    if (i >= cnt) return;
    int node = list ? list[i] : i;
    int quad = lane >> 4;
    int ql   = lane & 15;
    int d = min(deg[node], CAP);
    int start = node * CAP;
    int end = start + d;
    const uint4* xr = (const uint4*)xh;
    float a0=0,a1=0,a2=0,a3=0,a4=0,a5=0,a6=0,a7=0;
    int e = start;
    for (; e + 7 < end; e += 8) {
        int i0 = col[e + quad];
        int i1 = col[e + 4 + quad];
        uint4 u0 = xr[(size_t)i0 * 16 + ql];
        uint4 u1 = xr[(size_t)i1 * 16 + ql];
        a0 += bf_lo(u0.x) + bf_lo(u1.x); a1 += bf_hi(u0.x) + bf_hi(u1.x);
        a2 += bf_lo(u0.y) + bf_lo(u1.y); a3 += bf_hi(u0.y) + bf_hi(u1.y);
        a4 += bf_lo(u0.z) + bf_lo(u1.z); a5 += bf_hi(u0.z) + bf_hi(u1.z);
        a6 += bf_lo(u0.w) + bf_lo(u1.w); a7 += bf_hi(u0.w) + bf_hi(u1.w);
    }
    for (; e + 3 < end; e += 4) {
        uint4 u = xr[(size_t)col[e + quad] * 16 + ql];
        a0 += bf_lo(u.x); a1 += bf_hi(u.x);
        a2 += bf_lo(u.y); a3 += bf_hi(u.y);
        a4 += bf_lo(u.z); a5 += bf_hi(u.z);
        a6 += bf_lo(u.w); a7 += bf_hi(u.w);
    }
    int rem = end - e;
    if (quad < rem) {
        uint4 u = xr[(size_t)col[e + quad] * 16 + ql];
        a0 += bf_lo(u.x); a1 += bf_hi(u.x);
        a2 += bf_lo(u.y); a3 += bf_hi(u.y);
        a4 += bf_lo(u.z); a5 += bf_hi(u.z);
        a6 += bf_lo(u.w); a7 += bf_hi(u.w);
    }
    a0 += __shfl_xor(a0, 16, 64); a0 += __shfl_xor(a0, 32, 64);
    a1 += __shfl_xor(a1, 16, 64); a1 += __shfl_xor(a1, 32, 64);
    a2 += __shfl_xor(a2, 16, 64); a2 += __shfl_xor(a2, 32, 64);
    a3 += __shfl_xor(a3, 16, 64); a3 += __shfl_xor(a3, 32, 64);
    a4 += __shfl_xor(a4, 16, 64); a4 += __shfl_xor(a4, 32, 64);
    a5 += __shfl_xor(a5, 16, 64); a5 += __shfl_xor(a5, 32, 64);
    a6 += __shfl_xor(a6, 16, 64); a6 += __shfl_xor(a6, 32, 64);
    a7 += __shfl_xor(a7, 16, 64); a7 += __shfl_xor(a7, 32, 64);
    if (quad == 0) {
        float inv = 1.0f / (float)max(d, 1);
        float m[8] = {a0*inv, a1*inv, a2*inv, a3*inv, a4*inv, a5*inv, a6*inv, a7*inv};
        ushort h[8], o[8];
        #pragma unroll
        for (int j = 0; j < 8; ++j) split_bf16(m[j], h[j], o[j]);
        size_t off = (size_t)node * C + ql * 8;
        *(uint4*)(aggh + off) = make_uint4((unsigned)h[0] | ((unsigned)h[1] << 16),
                                           (unsigned)h[2] | ((unsigned)h[3] << 16),
                                           (unsigned)h[4] | ((unsigned)h[5] << 16),
                                           (unsigned)h[6] | ((unsigned)h[7] << 16));
        *(uint4*)(aggl + off) = make_uint4((unsigned)o[0] | ((unsigned)o[1] << 16),
                                           (unsigned)o[2] | ((unsigned)o[3] << 16),
                                           (unsigned)o[4] | ((unsigned)o[5] << 16),
                                           (unsigned)o[6] | ((unsigned)o[7] << 16));
    }
}

// ---- fused dual GEMM + bias + PReLU via split-bf16 MFMA ----
// out = prelu( A@Wl.T + bl + X@Wr.T ); operands AND weights pre-split hi/lo (row-major).
// list!=null: rows come from list[] (A gathered at list rows; agg operand G is indexed
// by ORIGINAL node id, matching agg's scattered writes); output scattered to original rows.

__global__ __launch_bounds__(256, 3)
void gemm_kernel(const ushort* __restrict__ Ah, const ushort* __restrict__ Al,
                 const ushort* __restrict__ Xh, const ushort* __restrict__ Xl,
                 const ushort* __restrict__ Wlh, const ushort* __restrict__ Wll,
                 const ushort* __restrict__ Wrh, const ushort* __restrict__ Wrl,
                 const float* __restrict__ bl, const float* __restrict__ slope,
                 const int* __restrict__ list, const int* __restrict__ countp,
                 float* __restrict__ outf, ushort* __restrict__ outh,
                 ushort* __restrict__ outl, int rows) {
    __shared__ ushort Ahi[64 * ASTRIDE];
    __shared__ ushort Alo[64 * ASTRIDE];
    int t = threadIdx.x;
    int lane = t & 63;
    int w = t >> 6;
    int l = lane & 15;
    int q = lane >> 4;
    int row0 = blockIdx.x * 64;
    int cnt = list ? min(*countp, rows) : rows;
    if (row0 >= cnt) return;

    f32x4 acc[4][2];
    #pragma unroll
    for (int mt = 0; mt < 4; ++mt)
        #pragma unroll
        for (int nt = 0; nt < 2; ++nt)
            acc[mt][nt] = (f32x4){0.f, 0.f, 0.f, 0.f};

    #pragma unroll
    for (int mat = 0; mat < 2; ++mat) {
        const ushort* WH = mat ? Wrh : Wlh;
        const ushort* WL = mat ? Wrl : Wll;
        const ushort* Ph = mat ? Xh : Ah;
        const ushort* Pl = mat ? Xl : Al;

        bf16x8 bhi[2][4], blo[2][4];
        #pragma unroll
        for (int nt = 0; nt < 2; ++nt) {
            int n = w * 32 + nt * 16 + l;
            const ushort* wp = WH + (size_t)n * C + q * 8;
            const ushort* wq = WL + (size_t)n * C + q * 8;
            #pragma unroll
            for (int kb = 0; kb < 4; ++kb) {
                bhi[nt][kb] = *(const bf16x8*)(wp + kb * 32);
                blo[nt][kb] = *(const bf16x8*)(wq + kb * 32);
            }
        }

        __syncthreads();
        int ar = t >> 2;
        int aq = t & 3;
        int ridx = min(row0 + ar, cnt - 1);
        int r = list ? list[ridx] : ridx;
        ushort* dh = Ahi + ar * ASTRIDE + aq * 32;
        ushort* dl = Alo + ar * ASTRIDE + aq * 32;
        const ushort* ph = Ph + (size_t)r * C + aq * 32;
        const ushort* pl = Pl + (size_t)r * C + aq * 32;
        #pragma unroll
        for (int i = 0; i < 4; ++i) {
            *(uint4*)(dh + i * 8) = *(const uint4*)(ph + i * 8);
            *(uint4*)(dl + i * 8) = *(const uint4*)(pl + i * 8);
        }
        __syncthreads();

        #pragma unroll
        for (int kb = 0; kb < 4; ++kb) {
            #pragma unroll
            for (int mt = 0; mt < 4; ++mt) {
                int off = (mt * 16 + l) * ASTRIDE + kb * 32 + q * 8;
                bf16x8 ahi = *(const bf16x8*)(Ahi + off);
                bf16x8 alo = *(const bf16x8*)(Alo + off);
                #pragma unroll
                for (int nt = 0; nt < 2; ++nt) {
                    acc[mt][nt] = __builtin_amdgcn_mfma_f32_16x16x32_bf16(ahi, bhi[nt][kb], acc[mt][nt], 0, 0, 0);
                    acc[mt][nt] = __builtin_amdgcn_mfma_f32_16x16x32_bf16(alo, bhi[nt][kb], acc[mt][nt], 0, 0, 0);
                    acc[mt][nt] = __builtin_amdgcn_mfma_f32_16x16x32_bf16(ahi, blo[nt][kb], acc[mt][nt], 0, 0, 0);
                }
            }
        }
    }

    // epilogue: bias + PReLU; fp32 (final) or hi/lo; list mode scatters to original rows
    #pragma unroll
    for (int nt = 0; nt < 2; ++nt) {
        int n = w * 32 + nt * 16 + l;
        float b = bl[n], s = slope[n];
        #pragma unroll
        for (int mt = 0; mt < 4; ++mt) {
            #pragma unroll
            for (int rg = 0; rg < 4; ++rg) {
                int ridx = row0 + mt * 16 + q * 4 + rg;
                if (ridx < cnt) {
                    int r = list ? list[ridx] : ridx;
                    float v = acc[mt][nt][rg] + b;
                    v = v > 0.f ? v : s * v;
                    if (outf) {
                        outf[(size_t)r * C + n] = v;
                    } else {
                        ushort hh, ll;
                        split_bf16(v, hh, ll);
                        outh[(size_t)r * C + n] = hh;
                        outl[(size_t)r * C + n] = ll;
                    }
                }
            }
        }
    }
}

// ---------------- launch ----------------

extern "C" void kernel_launch(void* const* d_in, const int* in_sizes, int n_in,
                              void* d_out, int out_size, void* d_ws, size_t ws_size,
                              hipStream_t stream) {
    const float* x   = (const float*)d_in[0];
    const int*   src = (const int*)d_in[1];
    const int*   dst = src + NE;
    const float* Wl[3] = {(const float*)d_in[3], (const float*)d_in[7],  (const float*)d_in[11]};
    const float* bl[3] = {(const float*)d_in[4], (const float*)d_in[8],  (const float*)d_in[12]};
    const float* Wr[3] = {(const float*)d_in[5], (const float*)d_in[9],  (const float*)d_in[13]};
    const float* sl[3] = {(const float*)d_in[6], (const float*)d_in[10], (const float*)d_in[14]};

    int*   deg     = (int*)d_ws;             // 50016
    int*   needed  = deg + 50016;            // 50016
    int*   cnt     = needed + 50016;         // 16 (one used)
    int*   pos     = cnt + 16;               // 800000
    int*   col     = pos + 800000;           // NN*CAP = 3.2M ints
    int*   list    = col + NN * CAP;         // 50016
    ushort* Whs    = (ushort*)(list + 50016);    // 6*16384 pre-split W hi
    ushort* Wls    = Whs + 6 * 16384;        // 6*16384 pre-split W lo
    ushort* Gh     = Wls + 6 * 16384;        // agg hi, NN*C
    ushort* Gl     = Gh + (size_t)NN * C;    // agg lo
    ushort* Ah     = Gl + (size_t)NN * C;    // ping hi
    ushort* Al     = Ah + (size_t)NN * C;    // ping lo
    ushort* Bh     = Al + (size_t)NN * C;    // pong hi
    ushort* Bl     = Bh + (size_t)NN * C;    // pong lo

    int rows_out = out_size / C;             // 1024

    // zero deg + needed + cnt (contiguous)
    hipMemsetAsync(deg, 0, (2 * 50016 + 16) * sizeof(int), stream);

    // W order: Wl0, Wr0, Wl1, Wr1, Wl2, Wr2
    prep_kernel<<<EB2 + SPLITB + WB, 256, 0, stream>>>(
        dst, x, Wl[0], Wr[0], Wl[1], Wr[1], Wl[2], Wr[2],
        deg, pos, Ah, Al, Whs, Wls);
    fill_kernel<<<EB4, 256, 0, stream>>>(src, dst, pos, col);

    // build layer-1 needed-node list (nodes 0..1023 + their in-neighbors)
    mark_kernel<<<(rows_out * CAP + 255) / 256, 256, 0, stream>>>(deg, col, needed, rows_out);
    compact_kernel<<<(NN + 255) / 256, 256, 0, stream>>>(needed, list, cnt);

    // layer 0 (full): A -> B
    agg_kernel<<<(NN + 3) / 4, 256, 0, stream>>>(Ah, deg, col, nullptr, nullptr, Gh, Gl, NN);
    gemm_kernel<<<(NN + 63) / 64, 256, 0, stream>>>(Gh, Gl, Ah, Al,
                                                    Whs + 0 * 16384, Wls + 0 * 16384,
                                                    Whs + 1 * 16384, Wls + 1 * 16384,
                                                    bl[0], sl[0], nullptr, nullptr,
                                                    nullptr, Bh, Bl, NN);

    // layer 1 (pruned to needed list): B -> A (scattered at original rows)
    agg_kernel<<<(NN + 3) / 4, 256, 0, stream>>>(Bh, deg, col, list, cnt, Gh, Gl, NN);
    gemm_kernel<<<(NN + 63) / 64, 256, 0, stream>>>(Gh, Gl, Bh, Bl,
                                                    Whs + 2 * 16384, Wls + 2 * 16384,
                                                    Whs + 3 * 16384, Wls + 3 * 16384,
                                                    bl[1], sl[1], list, cnt,
                                                    nullptr, Ah, Al, NN);

    // layer 2 (first rows_out nodes): A -> d_out
    agg_kernel<<<(rows_out + 3) / 4, 256, 0, stream>>>(Ah, deg, col, nullptr, nullptr,
                                                       Gh, Gl, rows_out);
    gemm_kernel<<<(rows_out + 63) / 64, 256, 0, stream>>>(Gh, Gl, Ah, Al,
                                                          Whs + 4 * 16384, Wls + 4 * 16384,
                                                          Whs + 5 * 16384, Wls + 5 * 16384,
                                                          bl[2], sl[2], nullptr, nullptr,
                                                          (float*)d_out, nullptr, nullptr,
                                                          rows_out);
}

// Round 17
// 285.136 us; speedup vs baseline: 1.0788x; 1.0273x over previous
//
#include <hip/hip_runtime.h>

#define NN 50000
#define NE 800000
#define C 128
#define CAP 64                           // fixed edge capacity per node (P(deg>=64) ~ 4e-18)
#define EB2 ((NE / 2 + 255) / 256)       // 1563 edge blocks (2 edges/thread)
#define SPLITB 1563                      // x-split blocks
#define WB 96                            // W-split blocks: 6*16384 floats / 4 / 256
#define MB4 ((NE / 4 + 255) / 256)       // 782 mark blocks (4 edges/thread)
#define EB4 ((NE / 4 + 255) / 256)       // 782 fill blocks (4 edges/thread)
#define CB  ((NN + 255) / 256)           // 196 compact blocks
#define ASTRIDE 136                      // bf16 elems per LDS A row

typedef __attribute__((ext_vector_type(8))) short bf16x8;
typedef __attribute__((ext_vector_type(4))) float f32x4;
typedef unsigned short ushort;

__device__ inline ushort bf16_rn(float f) {
    unsigned u = __builtin_bit_cast(unsigned, f);
    u += 0x7FFF + ((u >> 16) & 1);
    return (ushort)(u >> 16);
}
__device__ inline void split_bf16(float f, ushort& hi, ushort& lo) {
    hi = bf16_rn(f);
    float hif = __builtin_bit_cast(float, (unsigned)hi << 16);
    lo = bf16_rn(f - hif);               // residual, ~2^-17 rel total
}
__device__ inline float bf_lo(unsigned u) { return __builtin_bit_cast(float, u << 16); }
__device__ inline float bf_hi(unsigned u) { return __builtin_bit_cast(float, u & 0xFFFF0000u); }

// ---- fused prep: count_pos + split x + split W + mark needed (all independent) ----

__global__ __launch_bounds__(256)
void prep_kernel(const int* __restrict__ src, const int* __restrict__ dst,
                 const float* __restrict__ x,
                 const float* __restrict__ W0, const float* __restrict__ W1,
                 const float* __restrict__ W2, const float* __restrict__ W3,
                 const float* __restrict__ W4, const float* __restrict__ W5,
                 int* __restrict__ deg, int* __restrict__ pos,
                 ushort* __restrict__ Ah, ushort* __restrict__ Al,
                 ushort* __restrict__ Wh, ushort* __restrict__ Wl,
                 int* __restrict__ needed, int rows_out) {
    int t = threadIdx.x;
    if (blockIdx.x < EB2) {
        // edge count phase: 2 edges/thread
        int e0 = (blockIdx.x * 256 + t) * 2;
        if (e0 < NE) {
            int2 d2 = *(const int2*)(dst + e0);
            int p0 = atomicAdd(&deg[d2.x], 1);
            int p1 = atomicAdd(&deg[d2.y], 1);
            *(int2*)(pos + e0) = make_int2(p0, p1);
        }
    } else if (blockIdx.x < EB2 + SPLITB) {
        // x split phase (grid-stride over 1.6M f32x4), row-major hi/lo
        int tid = (blockIdx.x - EB2) * 256 + t;
        const int total = NN * C / 4;
        for (int i = tid; i < total; i += SPLITB * 256) {
            f32x4 v = ((const f32x4*)x)[i];
            ushort h0, h1, h2, h3, l0, l1, l2, l3;
            split_bf16(v.x, h0, l0);
            split_bf16(v.y, h1, l1);
            split_bf16(v.z, h2, l2);
            split_bf16(v.w, h3, l3);
            *(uint2*)(Ah + (size_t)i * 4) = make_uint2((unsigned)h0 | ((unsigned)h1 << 16),
                                                       (unsigned)h2 | ((unsigned)h3 << 16));
            *(uint2*)(Al + (size_t)i * 4) = make_uint2((unsigned)l0 | ((unsigned)l1 << 16),
                                                       (unsigned)l2 | ((unsigned)l3 << 16));
        }
    } else if (blockIdx.x < EB2 + SPLITB + WB) {
        // W split phase: 6 matrices x 16384 floats
        const float* Ws[6] = {W0, W1, W2, W3, W4, W5};
        int i = (blockIdx.x - EB2 - SPLITB) * 256 + t;
        int mat = i >> 12;
        f32x4 v = ((const f32x4*)Ws[mat])[i & 4095];
        ushort h0, h1, h2, h3, l0, l1, l2, l3;
        split_bf16(v.x, h0, l0);
        split_bf16(v.y, h1, l1);
        split_bf16(v.z, h2, l2);
        split_bf16(v.w, h3, l3);
        *(uint2*)(Wh + (size_t)i * 4) = make_uint2((unsigned)h0 | ((unsigned)h1 << 16),
                                                   (unsigned)h2 | ((unsigned)h3 << 16));
        *(uint2*)(Wl + (size_t)i * 4) = make_uint2((unsigned)l0 | ((unsigned)l1 << 16),
                                                   (unsigned)l2 | ((unsigned)l3 << 16));
    } else {
        // mark phase: needed[src] for edges landing in the output window (edge-list based,
        // no dependency on col). 4 edges/thread.
        int e0 = ((blockIdx.x - EB2 - SPLITB - WB) * 256 + t) * 4;
        if (e0 < NE) {
            int4 da = *(const int4*)(dst + e0);
            int4 sa = *(const int4*)(src + e0);
            if (da.x < rows_out) needed[sa.x] = 1;
            if (da.y < rows_out) needed[sa.y] = 1;
            if (da.z < rows_out) needed[sa.z] = 1;
            if (da.w < rows_out) needed[sa.w] = 1;
        }
    }
}

// ---- fused fill + compact (both depend only on prep) ----
// Blocks [0,EB4): bucket placement (stores independent of atomics).
// Blocks [EB4,EB4+CB): compact needed -> list (nodes < rows_out always included).

__global__ __launch_bounds__(256)
void fill_kernel(const int* __restrict__ src, const int* __restrict__ dst,
                 const int* __restrict__ pos, int* __restrict__ col,
                 const int* __restrict__ needed, int* __restrict__ list,
                 int* __restrict__ cnt, int rows_out) {
    int t = threadIdx.x;
    if (blockIdx.x < EB4) {
        int e0 = (blockIdx.x * 256 + t) * 4;
        if (e0 >= NE) return;
        int4 da = *(const int4*)(dst + e0);
        int4 sa = *(const int4*)(src + e0);
        int4 pa = *(const int4*)(pos + e0);
        if (pa.x < CAP) col[da.x * CAP + pa.x] = sa.x;
        if (pa.y < CAP) col[da.y * CAP + pa.y] = sa.y;
        if (pa.z < CAP) col[da.z * CAP + pa.z] = sa.z;
        if (pa.w < CAP) col[da.w * CAP + pa.w] = sa.w;
    } else {
        int i = (blockIdx.x - EB4) * 256 + t;
        if (i < NN && (i < rows_out || needed[i])) {
            int p = atomicAdd(cnt, 1);
            list[p] = i;
        }
    }
}

// ---- mean aggregation: one wave per (listed) node, 4 edge-rows per VMEM instr ----
// Row = 256 B of bf16-hi. 16 lanes x uint4 per edge-row; quad = lane>>4 picks edge.
// list!=null: process list[i] nodes (worst-case grid, early exit on *countp).
// Epilogue: mean -> split hi/lo -> 16B stores at ORIGINAL node offsets.

__global__ __launch_bounds__(256)
void agg_kernel(const ushort* __restrict__ xh, const int* __restrict__ deg,
                const int* __restrict__ col,
                const int* __restrict__ list, const int* __restrict__ countp,
                ushort* __restrict__ aggh, ushort* __restrict__ aggl, int nodes) {
    int i = (blockIdx.x * blockDim.x + threadIdx.x) >> 6;
    int lane = threadIdx.x & 63;
    int cnt = list ? *countp : nodes;
    if (i >= cnt) return;
    int node = list ? list[i] : i;
    int quad = lane >> 4;
    int ql   = lane & 15;
    int d = min(deg[node], CAP);
    int start = node * CAP;
    int end = start + d;
    const uint4* xr = (const uint4*)xh;
    float a0=0,a1=0,a2=0,a3=0,a4=0,a5=0,a6=0,a7=0;
    int e = start;
    for (; e + 7 < end; e += 8) {
        int i0 = col[e + quad];
        int i1 = col[e + 4 + quad];
        uint4 u0 = xr[(size_t)i0 * 16 + ql];
        uint4 u1 = xr[(size_t)i1 * 16 + ql];
        a0 += bf_lo(u0.x) + bf_lo(u1.x); a1 += bf_hi(u0.x) + bf_hi(u1.x);
        a2 += bf_lo(u0.y) + bf_lo(u1.y); a3 += bf_hi(u0.y) + bf_hi(u1.y);
        a4 += bf_lo(u0.z) + bf_lo(u1.z); a5 += bf_hi(u0.z) + bf_hi(u1.z);
        a6 += bf_lo(u0.w) + bf_lo(u1.w); a7 += bf_hi(u0.w) + bf_hi(u1.w);
    }
    for (; e + 3 < end; e += 4) {
        uint4 u = xr[(size_t)col[e + quad] * 16 + ql];
        a0 += bf_lo(u.x); a1 += bf_hi(u.x);
        a2 += bf_lo(u.y); a3 += bf_hi(u.y);
        a4 += bf_lo(u.z); a5 += bf_hi(u.z);
        a6 += bf_lo(u.w); a7 += bf_hi(u.w);
    }
    int rem = end - e;
    if (quad < rem) {
        uint4 u = xr[(size_t)col[e + quad] * 16 + ql];
        a0 += bf_lo(u.x); a1 += bf_hi(u.x);
        a2 += bf_lo(u.y); a3 += bf_hi(u.y);
        a4 += bf_lo(u.z); a5 += bf_hi(u.z);
        a6 += bf_lo(u.w); a7 += bf_hi(u.w);
    }
    a0 += __shfl_xor(a0, 16, 64); a0 += __shfl_xor(a0, 32, 64);
    a1 += __shfl_xor(a1, 16, 64); a1 += __shfl_xor(a1, 32, 64);
    a2 += __shfl_xor(a2, 16, 64); a2 += __shfl_xor(a2, 32, 64);
    a3 += __shfl_xor(a3, 16, 64); a3 += __shfl_xor(a3, 32, 64);
    a4 += __shfl_xor(a4, 16, 64); a4 += __shfl_xor(a4, 32, 64);
    a5 += __shfl_xor(a5, 16, 64); a5 += __shfl_xor(a5, 32, 64);
    a6 += __shfl_xor(a6, 16, 64); a6 += __shfl_xor(a6, 32, 64);
    a7 += __shfl_xor(a7, 16, 64); a7 += __shfl_xor(a7, 32, 64);
    if (quad == 0) {
        float inv = 1.0f / (float)max(d, 1);
        float m[8] = {a0*inv, a1*inv, a2*inv, a3*inv, a4*inv, a5*inv, a6*inv, a7*inv};
        ushort h[8], o[8];
        #pragma unroll
        for (int j = 0; j < 8; ++j) split_bf16(m[j], h[j], o[j]);
        size_t off = (size_t)node * C + ql * 8;
        *(uint4*)(aggh + off) = make_uint4((unsigned)h[0] | ((unsigned)h[1] << 16),
                                           (unsigned)h[2] | ((unsigned)h[3] << 16),
                                           (unsigned)h[4] | ((unsigned)h[5] << 16),
                                           (unsigned)h[6] | ((unsigned)h[7] << 16));
        *(uint4*)(aggl + off) = make_uint4((unsigned)o[0] | ((unsigned)o[1] << 16),
                                           (unsigned)o[2] | ((unsigned)o[3] << 16),
                                           (unsigned)o[4] | ((unsigned)o[5] << 16),
                                           (unsigned)o[6] | ((unsigned)o[7] << 16));
    }
}

// ---- fused dual GEMM + bias + PReLU via split-bf16 MFMA ----
// out = prelu( A@Wl.T + bl + X@Wr.T ); operands AND weights pre-split hi/lo (row-major).
// list!=null: rows from list[]; output scattered to original rows.
// launch_bounds (256,4): 4 blocks/CU (LDS 4x34.8=139KB<160KB, VGPR<=128).

__global__ __launch_bounds__(256, 4)
void gemm_kernel(const ushort* __restrict__ Ah, const ushort* __restrict__ Al,
                 const ushort* __restrict__ Xh, const ushort* __restrict__ Xl,
                 const ushort* __restrict__ Wlh, const ushort* __restrict__ Wll,
                 const ushort* __restrict__ Wrh, const ushort* __restrict__ Wrl,
                 const float* __restrict__ bl, const float* __restrict__ slope,
                 const int* __restrict__ list, const int* __restrict__ countp,
                 float* __restrict__ outf, ushort* __restrict__ outh,
                 ushort* __restrict__ outl, int rows) {
    __shared__ ushort Ahi[64 * ASTRIDE];
    __shared__ ushort Alo[64 * ASTRIDE];
    int t = threadIdx.x;
    int lane = t & 63;
    int w = t >> 6;
    int l = lane & 15;
    int q = lane >> 4;
    int row0 = blockIdx.x * 64;
    int cnt = list ? min(*countp, rows) : rows;
    if (row0 >= cnt) return;

    f32x4 acc[4][2];
    #pragma unroll
    for (int mt = 0; mt < 4; ++mt)
        #pragma unroll
        for (int nt = 0; nt < 2; ++nt)
            acc[mt][nt] = (f32x4){0.f, 0.f, 0.f, 0.f};

    #pragma unroll
    for (int mat = 0; mat < 2; ++mat) {
        const ushort* WH = mat ? Wrh : Wlh;
        const ushort* WL = mat ? Wrl : Wll;
        const ushort* Ph = mat ? Xh : Ah;
        const ushort* Pl = mat ? Xl : Al;

        bf16x8 bhi[2][4], blo[2][4];
        #pragma unroll
        for (int nt = 0; nt < 2; ++nt) {
            int n = w * 32 + nt * 16 + l;
            const ushort* wp = WH + (size_t)n * C + q * 8;
            const ushort* wq = WL + (size_t)n * C + q * 8;
            #pragma unroll
            for (int kb = 0; kb < 4; ++kb) {
                bhi[nt][kb] = *(const bf16x8*)(wp + kb * 32);
                blo[nt][kb] = *(const bf16x8*)(wq + kb * 32);
            }
        }

        __syncthreads();
        int ar = t >> 2;
        int aq = t & 3;
        int ridx = min(row0 + ar, cnt - 1);
        int r = list ? list[ridx] : ridx;
        ushort* dh = Ahi + ar * ASTRIDE + aq * 32;
        ushort* dl = Alo + ar * ASTRIDE + aq * 32;
        const ushort* ph = Ph + (size_t)r * C + aq * 32;
        const ushort* pl = Pl + (size_t)r * C + aq * 32;
        #pragma unroll
        for (int i = 0; i < 4; ++i) {
            *(uint4*)(dh + i * 8) = *(const uint4*)(ph + i * 8);
            *(uint4*)(dl + i * 8) = *(const uint4*)(pl + i * 8);
        }
        __syncthreads();

        #pragma unroll
        for (int kb = 0; kb < 4; ++kb) {
            #pragma unroll
            for (int mt = 0; mt < 4; ++mt) {
                int off = (mt * 16 + l) * ASTRIDE + kb * 32 + q * 8;
                bf16x8 ahi = *(const bf16x8*)(Ahi + off);
                bf16x8 alo = *(const bf16x8*)(Alo + off);
                #pragma unroll
                for (int nt = 0; nt < 2; ++nt) {
                    acc[mt][nt] = __builtin_amdgcn_mfma_f32_16x16x32_bf16(ahi, bhi[nt][kb], acc[mt][nt], 0, 0, 0);
                    acc[mt][nt] = __builtin_amdgcn_mfma_f32_16x16x32_bf16(alo, bhi[nt][kb], acc[mt][nt], 0, 0, 0);
                    acc[mt][nt] = __builtin_amdgcn_mfma_f32_16x16x32_bf16(ahi, blo[nt][kb], acc[mt][nt], 0, 0, 0);
                }
            }
        }
    }

    #pragma unroll
    for (int nt = 0; nt < 2; ++nt) {
        int n = w * 32 + nt * 16 + l;
        float b = bl[n], s = slope[n];
        #pragma unroll
        for (int mt = 0; mt < 4; ++mt) {
            #pragma unroll
            for (int rg = 0; rg < 4; ++rg) {
                int ridx = row0 + mt * 16 + q * 4 + rg;
                if (ridx < cnt) {
                    int r = list ? list[ridx] : ridx;
                    float v = acc[mt][nt][rg] + b;
                    v = v > 0.f ? v : s * v;
                    if (outf) {
                        outf[(size_t)r * C + n] = v;
                    } else {
                        ushort hh, ll;
                        split_bf16(v, hh, ll);
                        outh[(size_t)r * C + n] = hh;
                        outl[(size_t)r * C + n] = ll;
                    }
                }
            }
        }
    }
}

// ---------------- launch ----------------

extern "C" void kernel_launch(void* const* d_in, const int* in_sizes, int n_in,
                              void* d_out, int out_size, void* d_ws, size_t ws_size,
                              hipStream_t stream) {
    const float* x   = (const float*)d_in[0];
    const int*   src = (const int*)d_in[1];
    const int*   dst = src + NE;
    const float* Wl[3] = {(const float*)d_in[3], (const float*)d_in[7],  (const float*)d_in[11]};
    const float* bl[3] = {(const float*)d_in[4], (const float*)d_in[8],  (const float*)d_in[12]};
    const float* Wr[3] = {(const float*)d_in[5], (const float*)d_in[9],  (const float*)d_in[13]};
    const float* sl[3] = {(const float*)d_in[6], (const float*)d_in[10], (const float*)d_in[14]};

    int*   deg     = (int*)d_ws;             // 50016
    int*   needed  = deg + 50016;            // 50016
    int*   cnt     = needed + 50016;         // 16 (one used)
    int*   pos     = cnt + 16;               // 800000
    int*   col     = pos + 800000;           // NN*CAP = 3.2M ints
    int*   list    = col + NN * CAP;         // 50016
    ushort* Whs    = (ushort*)(list + 50016);    // 6*16384 pre-split W hi
    ushort* Wls    = Whs + 6 * 16384;        // 6*16384 pre-split W lo
    ushort* Gh     = Wls + 6 * 16384;        // agg hi, NN*C
    ushort* Gl     = Gh + (size_t)NN * C;    // agg lo
    ushort* Ah     = Gl + (size_t)NN * C;    // ping hi
    ushort* Al     = Ah + (size_t)NN * C;    // ping lo
    ushort* Bh     = Al + (size_t)NN * C;    // pong hi
    ushort* Bl     = Bh + (size_t)NN * C;    // pong lo

    int rows_out = out_size / C;             // 1024

    // zero deg + needed + cnt (contiguous)
    hipMemsetAsync(deg, 0, (2 * 50016 + 16) * sizeof(int), stream);

    // W order: Wl0, Wr0, Wl1, Wr1, Wl2, Wr2
    prep_kernel<<<EB2 + SPLITB + WB + MB4, 256, 0, stream>>>(
        src, dst, x, Wl[0], Wr[0], Wl[1], Wr[1], Wl[2], Wr[2],
        deg, pos, Ah, Al, Whs, Wls, needed, rows_out);
    fill_kernel<<<EB4 + CB, 256, 0, stream>>>(src, dst, pos, col, needed, list, cnt, rows_out);

    // layer 0 (full): A -> B
    agg_kernel<<<(NN + 3) / 4, 256, 0, stream>>>(Ah, deg, col, nullptr, nullptr, Gh, Gl, NN);
    gemm_kernel<<<(NN + 63) / 64, 256, 0, stream>>>(Gh, Gl, Ah, Al,
                                                    Whs + 0 * 16384, Wls + 0 * 16384,
                                                    Whs + 1 * 16384, Wls + 1 * 16384,
                                                    bl[0], sl[0], nullptr, nullptr,
                                                    nullptr, Bh, Bl, NN);

    // layer 1 (pruned to needed list): B -> A (scattered at original rows)
    agg_kernel<<<(NN + 3) / 4, 256, 0, stream>>>(Bh, deg, col, list, cnt, Gh, Gl, NN);
    gemm_kernel<<<(NN + 63) / 64, 256, 0, stream>>>(Gh, Gl, Bh, Bl,
                                                    Whs + 2 * 16384, Wls + 2 * 16384,
                                                    Whs + 3 * 16384, Wls + 3 * 16384,
                                                    bl[1], sl[1], list, cnt,
                                                    nullptr, Ah, Al, NN);

    // layer 2 (first rows_out nodes): A -> d_out
    agg_kernel<<<(rows_out + 3) / 4, 256, 0, stream>>>(Ah, deg, col, nullptr, nullptr,
                                                       Gh, Gl, rows_out);
    gemm_kernel<<<(rows_out + 63) / 64, 256, 0, stream>>>(Gh, Gl, Ah, Al,
                                                          Whs + 4 * 16384, Wls + 4 * 16384,
                                                          Whs + 5 * 16384, Wls + 5 * 16384,
                                                          bl[2], sl[2], nullptr, nullptr,
                                                          (float*)d_out, nullptr, nullptr,
                                                          rows_out);
}